// Round 5
// baseline (14799.091 us; speedup 1.0000x reference)
//
#include <hip/hip_runtime.h>
#include <math.h>

#define NPTS   8192
#define NB     2
#define NROWS  (NB*NPTS)       // 16384 rows per direction
#define ROWS_PER_WAVE  8
#define WAVES_PER_BLOCK 4
#define ROWS_PER_BLOCK (ROWS_PER_WAVE*WAVES_PER_BLOCK)   // 32
#define BLURF  0.001f
#define LOG2E  1.4426950408889634f
#define LN2F   0.6931471805599453f
#define BLOGF  (-9.010913347279288f)   // -log(8192)

#if __has_builtin(__builtin_amdgcn_sqrtf)
#define FAST_SQRT(x) __builtin_amdgcn_sqrtf(x)
#else
#define FAST_SQRT(x) sqrtf(x)
#endif

// ---------------------------------------------------------------- diameter
__global__ __launch_bounds__(1024) void minmax_kernel(
    const float* __restrict__ x, const float* __restrict__ y,
    float* __restrict__ diam_out)
{
    int tid = threadIdx.x;
    float mx[3] = {-INFINITY, -INFINITY, -INFINITY};
    float mn[3] = { INFINITY,  INFINITY,  INFINITY};
    for (int p = tid; p < NROWS; p += 1024) {
        #pragma unroll
        for (int d = 0; d < 3; ++d) {
            float a = x[p*3+d], b = y[p*3+d];
            mx[d] = fmaxf(mx[d], fmaxf(a, b));
            mn[d] = fminf(mn[d], fminf(a, b));
        }
    }
    #pragma unroll
    for (int off = 32; off >= 1; off >>= 1) {
        #pragma unroll
        for (int d = 0; d < 3; ++d) {
            mx[d] = fmaxf(mx[d], __shfl_xor(mx[d], off));
            mn[d] = fminf(mn[d], __shfl_xor(mn[d], off));
        }
    }
    __shared__ float smx[16][3], smn[16][3];
    int wid = tid >> 6, lane = tid & 63;
    if (lane == 0) {
        #pragma unroll
        for (int d = 0; d < 3; ++d) { smx[wid][d] = mx[d]; smn[wid][d] = mn[d]; }
    }
    __syncthreads();
    if (tid == 0) {
        float dm = 0.0f;
        #pragma unroll
        for (int d = 0; d < 3; ++d) {
            float a = -INFINITY, b = INFINITY;
            for (int w = 0; w < 16; ++w) {
                a = fmaxf(a, smx[w][d]); b = fminf(b, smn[w][d]);
            }
            dm = fmaxf(dm, a - b);
        }
        diam_out[0] = dm;
    }
}

// ------------------------------------------------- pack points into float4
__global__ __launch_bounds__(256) void pack_pts_kernel(
    const float* __restrict__ x, const float* __restrict__ y,
    float4* __restrict__ px4, float4* __restrict__ py4)
{
    int gid = blockIdx.x * 256 + threadIdx.x;   // 0..32767
    int sel = gid >> 14;
    int idx = gid & 16383;
    const float* p = sel ? y : x;
    float4 o;
    o.x = p[idx*3+0]; o.y = p[idx*3+1]; o.z = p[idx*3+2]; o.w = 0.0f;
    (sel ? py4 : px4)[idx] = o;
}

// ---------------------------------------- fold per-pass log-weight into .w
// py4.w <- (BLOGF + g[j]/eps)*LOG2E  (consumed by dir0: rows=x, cols=y)
// px4.w <- (BLOGF + f[j]/eps)*LOG2E  (consumed by dir1: rows=y, cols=x)
__global__ __launch_bounds__(256) void prep_kernel(
    float4* __restrict__ px4, float4* __restrict__ py4,
    const float* __restrict__ f, const float* __restrict__ g,
    const float* __restrict__ diam_ptr, float scale_k)
{
    int gid = blockIdx.x * 256 + threadIdx.x;   // 0..32767
    const float eps     = fmaxf(diam_ptr[0] * scale_k, BLURF);
    const float inv_eps = 1.0f / eps;
    int sel = gid >> 14;
    int idx = gid & 16383;
    const float* h = sel ? f : g;
    float hv = h ? h[idx] * inv_eps : 0.0f;
    (sel ? px4 : py4)[idx].w = (BLOGF + hv) * LOG2E;
}

// ------------------------------------------------------------- softmin pass
// out[b,i] = -eps*ln2*log2( sum_j 2^{cols.w[j] - C_ij*log2e/eps} )
__global__ __launch_bounds__(256, 4) void softmin_kernel(
    const float* __restrict__ rows0, const float* __restrict__ rows1,
    const float4* __restrict__ cols0, const float4* __restrict__ cols1,
    const float* __restrict__ old0, const float* __restrict__ old1,
    float* __restrict__ out0, float* __restrict__ out1,
    int do_avg, const float* __restrict__ diam_ptr, float scale_k)
{
    const int dir = blockIdx.z;
    const float*  rows = dir ? rows1 : rows0;
    const float4* cols = dir ? cols1 : cols0;
    const float*  oldf = dir ? old1 : old0;
    float*        outf = dir ? out1 : out0;

    const float eps     = fmaxf(diam_ptr[0] * scale_k, BLURF);
    const float inv_eps = 1.0f / eps;
    const float nie2    = -LOG2E * inv_eps;

    const int tid  = threadIdx.x, lane = tid & 63, wid = tid >> 6;
    const int i0   = blockIdx.x * ROWS_PER_BLOCK;
    const int b    = i0 >> 13;
    const int rowbase = i0 + wid * ROWS_PER_WAVE;   // within [b*NPTS, (b+1)*NPTS)

    float px[8], py[8], pz[8];
    #pragma unroll
    for (int r = 0; r < 8; ++r) {
        int o = (rowbase + r) * 3;
        px[r] = rows[o]; py[r] = rows[o+1]; pz[r] = rows[o+2];
    }

    float m[8], s[8];
    #pragma unroll
    for (int r = 0; r < 8; ++r) { m[r] = -INFINITY; s[r] = 0.0f; }

    const float4* csrc = cols + b * NPTS;

    for (int c0 = 0; c0 < NPTS; c0 += 512) {
        float4 cp[8];
        #pragma unroll
        for (int k = 0; k < 8; ++k) cp[k] = csrc[c0 + k*64 + lane];
        #pragma unroll
        for (int r = 0; r < 8; ++r) {
            float w[8];
            #pragma unroll
            for (int k = 0; k < 8; ++k) {
                float dx = px[r]-cp[k].x, dy = py[r]-cp[k].y, dz = pz[r]-cp[k].z;
                float sq = fmaf(dx,dx,fmaf(dy,dy,dz*dz));
                w[k] = fmaf(FAST_SQRT(sq), nie2, cp[k].w);
            }
            float a01 = fmaxf(w[0],w[1]), a23 = fmaxf(w[2],w[3]);
            float a45 = fmaxf(w[4],w[5]), a67 = fmaxf(w[6],w[7]);
            float gm  = fmaxf(fmaxf(a01,a23), fmaxf(a45,a67));
            float mu  = fmaxf(m[r], gm);
            float scale = exp2f(m[r] - mu);        // exp2(-inf)=0 on first group
            float e0 = exp2f(w[0]-mu) + exp2f(w[1]-mu);
            float e1 = exp2f(w[2]-mu) + exp2f(w[3]-mu);
            float e2 = exp2f(w[4]-mu) + exp2f(w[5]-mu);
            float e3 = exp2f(w[6]-mu) + exp2f(w[7]-mu);
            s[r] = fmaf(s[r], scale, (e0+e1)+(e2+e3));
            m[r] = mu;
        }
    }

    // cross-lane LSE merge (64-lane butterfly)
    #pragma unroll
    for (int r = 0; r < 8; ++r) {
        float mm = m[r], ss = s[r];
        #pragma unroll
        for (int off = 32; off >= 1; off >>= 1) {
            float mo = __shfl_xor(mm, off);
            float so = __shfl_xor(ss, off);
            float mu = fmaxf(mm, mo);
            ss = fmaf(ss, exp2f(mm-mu), so * exp2f(mo-mu));
            mm = mu;
        }
        m[r] = mm; s[r] = ss;
    }

    if (lane == 0) {
        #pragma unroll
        for (int r = 0; r < 8; ++r) {
            float res = -eps * LN2F * (m[r] + log2f(s[r]));
            int oidx = rowbase + r;
            if (do_avg) res = 0.5f * (oldf[oidx] + res);
            outf[oidx] = res;
        }
    }
}

// ----------------------------------------------------------------- reduce
__global__ __launch_bounds__(1024) void reduce_kernel(
    const float* __restrict__ f, const float* __restrict__ g,
    float* __restrict__ out)
{
    int tid = threadIdx.x;
    float acc = 0.0f;
    for (int i = tid; i < NROWS; i += 1024) acc += f[i] + g[i];
    #pragma unroll
    for (int off = 32; off >= 1; off >>= 1) acc += __shfl_xor(acc, off);
    __shared__ float sw[16];
    int wid = tid >> 6, lane = tid & 63;
    if (lane == 0) sw[wid] = acc;
    __syncthreads();
    if (tid == 0) {
        float t = 0.0f;
        for (int w = 0; w < 16; ++w) t += sw[w];
        out[0] = t * (1.0f / (float)NROWS);   // mean over B of (sum a*f + sum b*g)
    }
}

// ----------------------------------------------------------------- launch
extern "C" void kernel_launch(void* const* d_in, const int* in_sizes, int n_in,
                              void* d_out, int out_size, void* d_ws, size_t ws_size,
                              hipStream_t stream)
{
    const float* x = (const float*)d_in[0];
    const float* y = (const float*)d_in[1];
    float* out = (float*)d_out;
    float* ws  = (float*)d_ws;

    float* diam = ws;                    // [16] (aligned pad)
    float* fa = ws + 16;                 // [16384]
    float* ga = fa + NROWS;
    float* fb = ga + NROWS;
    float* gb = fb + NROWS;
    float4* px4 = (float4*)(gb + NROWS); // 16384 float4 (offset 16B-aligned)
    float4* py4 = px4 + NROWS;

    minmax_kernel<<<1, 1024, 0, stream>>>(x, y, diam);
    pack_pts_kernel<<<(NROWS*2)/256, 256, 0, stream>>>(x, y, px4, py4);

    dim3 sgrid(NROWS/ROWS_PER_BLOCK, 1, 2);
    const int pgrid = (NROWS*2)/256;

    // init: f0 = softmin(eps0, Cxy, b_log), g0 = softmin(eps0, Cyx, a_log)
    prep_kernel<<<pgrid, 256, 0, stream>>>(px4, py4, nullptr, nullptr, diam, 1.0f);
    softmin_kernel<<<sgrid, 256, 0, stream>>>(x, y, py4, px4,
        nullptr, nullptr, fa, ga, 0, diam, 1.0f);

    // 96 Jacobi steps with eps annealing: eps_k = max(diam * 0.9^k, blur)
    double sk = 1.0;
    for (int k = 0; k < 96; ++k) {
        prep_kernel<<<pgrid, 256, 0, stream>>>(px4, py4, fa, ga, diam, (float)sk);
        softmin_kernel<<<sgrid, 256, 0, stream>>>(x, y, py4, px4,
            fa, ga, fb, gb, 1, diam, (float)sk);
        float* t;
        t = fa; fa = fb; fb = t;
        t = ga; ga = gb; gb = t;
        sk *= 0.9;
    }

    // final extrapolation at eps = blur (scale 0 -> fmax picks BLUR)
    prep_kernel<<<pgrid, 256, 0, stream>>>(px4, py4, fa, ga, diam, 0.0f);
    softmin_kernel<<<sgrid, 256, 0, stream>>>(x, y, py4, px4,
        nullptr, nullptr, fb, gb, 0, diam, 0.0f);

    reduce_kernel<<<1, 1024, 0, stream>>>(fb, gb, out);
}

// Round 10
// 8941.864 us; speedup vs baseline: 1.6550x; 1.6550x over previous
//
#include <hip/hip_runtime.h>
#include <math.h>

#define NPTS   8192
#define NB     2
#define NROWS  (NB*NPTS)       // 16384 points per cloud (B=2 x 8192)
#define ROWS_PER_WAVE  8
#define WAVES_PER_BLOCK 4
#define ROWS_PER_BLOCK (ROWS_PER_WAVE*WAVES_PER_BLOCK)   // 32
#define BLURF  0.001f
#define LOG2E  1.4426950408889634f
#define LN2F   0.6931471805599453f
#define BLOGF  (-9.010913347279288f)   // -log(8192)

typedef float v2f __attribute__((ext_vector_type(2)));

#if __has_builtin(__builtin_amdgcn_sqrtf)
#define FAST_SQRT(x) __builtin_amdgcn_sqrtf(x)
#else
#define FAST_SQRT(x) sqrtf(x)
#endif
#if __has_builtin(__builtin_amdgcn_exp2f)
#define RAW_EXP2(x) __builtin_amdgcn_exp2f(x)
#else
#define RAW_EXP2(x) exp2f(x)
#endif
#if __has_builtin(__builtin_amdgcn_logf)
#define RAW_LOG2(x) __builtin_amdgcn_logf(x)
#else
#define RAW_LOG2(x) log2f(x)
#endif
#if __has_builtin(__builtin_elementwise_max)
#define PKMAX(a,b) __builtin_elementwise_max(a,b)
#else
static __device__ __forceinline__ v2f PKMAX(v2f a, v2f b){ v2f r; r.x=fmaxf(a.x,b.x); r.y=fmaxf(a.y,b.y); return r; }
#endif

// ---- workspace layout (floats). Total = 16 + 12*NROWS = 196624 (= 786 KB, same as prior rounds)
#define WS_DIAM 0
#define WS_FA   16
#define WS_GA   (WS_FA + NROWS)
#define WS_XX   (WS_GA + NROWS)      // x-cloud coords SoA (X,Y,Z contiguous)
#define WS_XY   (WS_XX + 3*NROWS)    // y-cloud coords SoA
#define WS_WXA  (WS_XY + 3*NROWS)    // folded f (consumed as cols of dir1), buffers A/B
#define WS_WXB  (WS_WXA + NROWS)
#define WS_WYA  (WS_WXB + NROWS)     // folded g (consumed as cols of dir0), buffers A/B
#define WS_WYB  (WS_WYA + NROWS)

// ---------------------------------------------------------------- diameter
__global__ __launch_bounds__(1024) void minmax_kernel(
    const float* __restrict__ x, const float* __restrict__ y,
    float* __restrict__ diam_out)
{
    int tid = threadIdx.x;
    float mx[3] = {-INFINITY, -INFINITY, -INFINITY};
    float mn[3] = { INFINITY,  INFINITY,  INFINITY};
    for (int p = tid; p < NROWS; p += 1024) {
        #pragma unroll
        for (int d = 0; d < 3; ++d) {
            float a = x[p*3+d], b = y[p*3+d];
            mx[d] = fmaxf(mx[d], fmaxf(a, b));
            mn[d] = fminf(mn[d], fminf(a, b));
        }
    }
    #pragma unroll
    for (int off = 32; off >= 1; off >>= 1) {
        #pragma unroll
        for (int d = 0; d < 3; ++d) {
            mx[d] = fmaxf(mx[d], __shfl_xor(mx[d], off));
            mn[d] = fminf(mn[d], __shfl_xor(mn[d], off));
        }
    }
    __shared__ float smx[16][3], smn[16][3];
    int wid = tid >> 6, lane = tid & 63;
    if (lane == 0) {
        #pragma unroll
        for (int d = 0; d < 3; ++d) { smx[wid][d] = mx[d]; smn[wid][d] = mn[d]; }
    }
    __syncthreads();
    if (tid == 0) {
        float dm = 0.0f;
        #pragma unroll
        for (int d = 0; d < 3; ++d) {
            float a = -INFINITY, b = INFINITY;
            for (int w = 0; w < 16; ++w) {
                a = fmaxf(a, smx[w][d]); b = fminf(b, smn[w][d]);
            }
            dm = fmaxf(dm, a - b);
        }
        diam_out[0] = dm;
    }
}

// --------------------------- pack AoS float3 points into SoA, init W = b_log
__global__ __launch_bounds__(256) void pack_pts_kernel(
    const float* __restrict__ x, const float* __restrict__ y,
    float* __restrict__ ws)
{
    int gid = blockIdx.x * 256 + threadIdx.x;   // 0..32767
    int sel = gid >> 14;
    int idx = gid & (NROWS-1);
    const float* p = sel ? y : x;
    int off = sel ? WS_XY : WS_XX;
    ws[off + idx]           = p[idx*3+0];
    ws[off +   NROWS + idx] = p[idx*3+1];
    ws[off + 2*NROWS + idx] = p[idx*3+2];
    ws[(sel ? WS_WYA : WS_WXA) + idx] = BLOGF * LOG2E;   // h=0 initial weights
}

// ------------------------------------------------------------- softmin pass
// out[b,i] = -eps*ln2*log2( sum_j 2^{W[j] - ||p_i - q_j||*log2e/eps} )
// dir 0: rows=x, cols=y(SoA)+Wy ; writes fa and folded Wx(nxt)
// dir 1: rows=y, cols=x(SoA)+Wx ; writes ga and folded Wy(nxt)
__global__ __launch_bounds__(256, 4) void softmin_kernel(
    const float* __restrict__ x, const float* __restrict__ y,
    float* __restrict__ ws, int cur,
    float scale_k, float scale_next, int do_avg)
{
    const int dir = blockIdx.z;
    const float* rows = dir ? y : x;

    const float diam      = ws[WS_DIAM];
    const float eps       = fmaxf(diam * scale_k, BLURF);
    const float nie2      = -LOG2E / eps;
    const float eps_next  = fmaxf(diam * scale_next, BLURF);
    const float ien_log2e = LOG2E / eps_next;

    const int tid = threadIdx.x, lane = tid & 63, wid = tid >> 6;
    const int i0  = blockIdx.x * ROWS_PER_BLOCK;
    const int b   = i0 >> 13;
    const int rowbase = i0 + wid * ROWS_PER_WAVE;

    // col SoA base pointers (v2f), per batch b
    const int cbase = dir ? WS_XX : WS_XY;
    const v2f* CX = ((const v2f*)(ws + cbase          )) + b*(NPTS/2);
    const v2f* CY = ((const v2f*)(ws + cbase +   NROWS)) + b*(NPTS/2);
    const v2f* CZ = ((const v2f*)(ws + cbase + 2*NROWS)) + b*(NPTS/2);
    const int wcur_off = dir ? (cur ? WS_WXB : WS_WXA) : (cur ? WS_WYB : WS_WYA);
    const int wnxt_off = dir ? (cur ? WS_WYA : WS_WYB) : (cur ? WS_WXA : WS_WXB);
    const v2f* CW = ((const v2f*)(ws + wcur_off)) + b*(NPTS/2);
    float* Wnxt = ws + wnxt_off;
    float* outf = ws + (dir ? WS_GA : WS_FA);

    float px[8], py[8], pz[8];
    #pragma unroll
    for (int r = 0; r < 8; ++r) {
        int o = (rowbase + r) * 3;
        px[r] = rows[o]; py[r] = rows[o+1]; pz[r] = rows[o+2];
    }

    v2f m2[8], s2[8];
    #pragma unroll
    for (int r = 0; r < 8; ++r) { m2[r] = (v2f){-INFINITY,-INFINITY}; s2[r] = (v2f){0.0f,0.0f}; }

    const v2f nie2v = {nie2, nie2};

    for (int c0 = 0; c0 < NPTS/2; c0 += 256) {     // 512 cols per iter
        v2f Xc[4], Yc[4], Zc[4], Wc[4];
        #pragma unroll
        for (int k = 0; k < 4; ++k) {
            int idx = c0 + k*64 + lane;
            Xc[k] = CX[idx]; Yc[k] = CY[idx]; Zc[k] = CZ[idx]; Wc[k] = CW[idx];
        }
        #pragma unroll
        for (int r = 0; r < 8; ++r) {
            const v2f prx = {px[r], px[r]}, pry = {py[r], py[r]}, prz = {pz[r], pz[r]};
            v2f w2[4];
            #pragma unroll
            for (int k = 0; k < 4; ++k) {
                v2f dx = Xc[k] - prx, dy = Yc[k] - pry, dz = Zc[k] - prz;
                v2f sq = dx*dx + dy*dy + dz*dz;
                v2f c2; c2.x = FAST_SQRT(sq.x); c2.y = FAST_SQRT(sq.y);
                w2[k] = c2 * nie2v + Wc[k];
            }
            v2f gm = PKMAX(PKMAX(w2[0], w2[1]), PKMAX(w2[2], w2[3]));
            v2f mu = PKMAX(m2[r], gm);
            v2f dm = m2[r] - mu;
            v2f e0 = w2[0] - mu, e1 = w2[1] - mu, e2 = w2[2] - mu, e3 = w2[3] - mu;
            float ex = (RAW_EXP2(e0.x) + RAW_EXP2(e1.x)) + (RAW_EXP2(e2.x) + RAW_EXP2(e3.x));
            float ey = (RAW_EXP2(e0.y) + RAW_EXP2(e1.y)) + (RAW_EXP2(e2.y) + RAW_EXP2(e3.y));
            s2[r].x = fmaf(s2[r].x, RAW_EXP2(dm.x), ex);
            s2[r].y = fmaf(s2[r].y, RAW_EXP2(dm.y), ey);
            m2[r] = mu;
        }
    }

    // merge packed halves, then 64-lane butterfly
    #pragma unroll
    for (int r = 0; r < 8; ++r) {
        float mm = fmaxf(m2[r].x, m2[r].y);
        float ss = s2[r].x * RAW_EXP2(m2[r].x - mm) + s2[r].y * RAW_EXP2(m2[r].y - mm);
        #pragma unroll
        for (int off = 32; off >= 1; off >>= 1) {
            float mo = __shfl_xor(mm, off);
            float so = __shfl_xor(ss, off);
            float mu = fmaxf(mm, mo);
            ss = fmaf(ss, RAW_EXP2(mm-mu), so * RAW_EXP2(mo-mu));
            mm = mu;
        }
        if (lane == 0) {
            float res = -eps * LN2F * (mm + RAW_LOG2(ss));
            int oidx = rowbase + r;
            if (do_avg) res = 0.5f * (outf[oidx] + res);   // in-place: element owned by this thread
            outf[oidx] = res;
            Wnxt[oidx] = fmaf(res, ien_log2e, BLOGF * LOG2E);  // fold for next pass
        }
    }
}

// ----------------------------------------------------------------- reduce
__global__ __launch_bounds__(1024) void reduce_kernel(
    const float* __restrict__ ws, float* __restrict__ out)
{
    const float* f = ws + WS_FA;
    const float* g = ws + WS_GA;
    int tid = threadIdx.x;
    float acc = 0.0f;
    for (int i = tid; i < NROWS; i += 1024) acc += f[i] + g[i];
    #pragma unroll
    for (int off = 32; off >= 1; off >>= 1) acc += __shfl_xor(acc, off);
    __shared__ float sw[16];
    int wid = tid >> 6, lane = tid & 63;
    if (lane == 0) sw[wid] = acc;
    __syncthreads();
    if (tid == 0) {
        float t = 0.0f;
        for (int w = 0; w < 16; ++w) t += sw[w];
        out[0] = t * (1.0f / (float)NROWS);   // mean over B of (sum a*f + sum b*g)
    }
}

// ----------------------------------------------------------------- launch
extern "C" void kernel_launch(void* const* d_in, const int* in_sizes, int n_in,
                              void* d_out, int out_size, void* d_ws, size_t ws_size,
                              hipStream_t stream)
{
    const float* x = (const float*)d_in[0];
    const float* y = (const float*)d_in[1];
    float* out = (float*)d_out;
    float* ws  = (float*)d_ws;

    minmax_kernel<<<1, 1024, 0, stream>>>(x, y, ws + WS_DIAM);
    pack_pts_kernel<<<(NROWS*2)/256, 256, 0, stream>>>(x, y, ws);

    dim3 sgrid(NROWS/ROWS_PER_BLOCK, 1, 2);
    int cur = 0;

    // init: f0,g0 at eps0; epilogue folds with eps of step 0 (= eps0 again)
    softmin_kernel<<<sgrid, 256, 0, stream>>>(x, y, ws, cur, 1.0f, 1.0f, 0);
    cur ^= 1;

    // 96 Jacobi steps; step k at eps_k = max(diam*0.9^k, blur); fold for k+1
    double sk = 1.0;
    for (int k = 0; k < 96; ++k) {
        float sn = (k < 95) ? (float)(sk * 0.9) : 0.0f;   // last folds at blur
        softmin_kernel<<<sgrid, 256, 0, stream>>>(x, y, ws, cur, (float)sk, sn, 1);
        cur ^= 1;
        sk *= 0.9;
    }

    // final extrapolation at eps = blur (fold output unused)
    softmin_kernel<<<sgrid, 256, 0, stream>>>(x, y, ws, cur, 0.0f, 0.0f, 0);

    reduce_kernel<<<1, 1024, 0, stream>>>(ws, out);
}

// Round 11
// 8932.444 us; speedup vs baseline: 1.6568x; 1.0011x over previous
//
#include <hip/hip_runtime.h>
#include <math.h>

#define NPTS   8192
#define NB     2
#define NROWS  (NB*NPTS)       // 16384 points per cloud (B=2 x 8192)
#define ROWS_PER_WAVE  4
#define WAVES_PER_BLOCK 4
#define ROWS_PER_BLOCK (ROWS_PER_WAVE*WAVES_PER_BLOCK)   // 16
#define BLURF  0.001f
#define LOG2E  1.4426950408889634f
#define LN2F   0.6931471805599453f
#define BLOGF  (-9.010913347279288f)   // -log(8192)
#define DEFER_THR 8.0f

typedef float v2f __attribute__((ext_vector_type(2)));

#if __has_builtin(__builtin_amdgcn_sqrtf)
#define FAST_SQRT(x) __builtin_amdgcn_sqrtf(x)
#else
#define FAST_SQRT(x) sqrtf(x)
#endif
#if __has_builtin(__builtin_amdgcn_exp2f)
#define RAW_EXP2(x) __builtin_amdgcn_exp2f(x)
#else
#define RAW_EXP2(x) exp2f(x)
#endif
#if __has_builtin(__builtin_amdgcn_logf)
#define RAW_LOG2(x) __builtin_amdgcn_logf(x)
#else
#define RAW_LOG2(x) log2f(x)
#endif
#if __has_builtin(__builtin_elementwise_max)
#define PKMAX(a,b) __builtin_elementwise_max(a,b)
#else
static __device__ __forceinline__ v2f PKMAX(v2f a, v2f b){ v2f r; r.x=fmaxf(a.x,b.x); r.y=fmaxf(a.y,b.y); return r; }
#endif

// ---- workspace layout (floats). Total = 16 + 12*NROWS = 196624 floats (786 KB)
#define WS_DIAM 0
#define WS_FA   16
#define WS_GA   (WS_FA + NROWS)
#define WS_XX   (WS_GA + NROWS)      // x-cloud coords SoA (X,Y,Z contiguous)
#define WS_XY   (WS_XX + 3*NROWS)    // y-cloud coords SoA
#define WS_WXA  (WS_XY + 3*NROWS)    // folded f (consumed as cols of dir1), buffers A/B
#define WS_WXB  (WS_WXA + NROWS)
#define WS_WYA  (WS_WXB + NROWS)     // folded g (consumed as cols of dir0), buffers A/B
#define WS_WYB  (WS_WYA + NROWS)

// ---------------------------------------------------------------- diameter
__global__ __launch_bounds__(1024) void minmax_kernel(
    const float* __restrict__ x, const float* __restrict__ y,
    float* __restrict__ diam_out)
{
    int tid = threadIdx.x;
    float mx[3] = {-INFINITY, -INFINITY, -INFINITY};
    float mn[3] = { INFINITY,  INFINITY,  INFINITY};
    for (int p = tid; p < NROWS; p += 1024) {
        #pragma unroll
        for (int d = 0; d < 3; ++d) {
            float a = x[p*3+d], b = y[p*3+d];
            mx[d] = fmaxf(mx[d], fmaxf(a, b));
            mn[d] = fminf(mn[d], fminf(a, b));
        }
    }
    #pragma unroll
    for (int off = 32; off >= 1; off >>= 1) {
        #pragma unroll
        for (int d = 0; d < 3; ++d) {
            mx[d] = fmaxf(mx[d], __shfl_xor(mx[d], off));
            mn[d] = fminf(mn[d], __shfl_xor(mn[d], off));
        }
    }
    __shared__ float smx[16][3], smn[16][3];
    int wid = tid >> 6, lane = tid & 63;
    if (lane == 0) {
        #pragma unroll
        for (int d = 0; d < 3; ++d) { smx[wid][d] = mx[d]; smn[wid][d] = mn[d]; }
    }
    __syncthreads();
    if (tid == 0) {
        float dm = 0.0f;
        #pragma unroll
        for (int d = 0; d < 3; ++d) {
            float a = -INFINITY, b = INFINITY;
            for (int w = 0; w < 16; ++w) {
                a = fmaxf(a, smx[w][d]); b = fminf(b, smn[w][d]);
            }
            dm = fmaxf(dm, a - b);
        }
        diam_out[0] = dm;
    }
}

// --------------------------- pack AoS float3 points into SoA, init W = b_log
__global__ __launch_bounds__(256) void pack_pts_kernel(
    const float* __restrict__ x, const float* __restrict__ y,
    float* __restrict__ ws)
{
    int gid = blockIdx.x * 256 + threadIdx.x;   // 0..32767
    int sel = gid >> 14;
    int idx = gid & (NROWS-1);
    const float* p = sel ? y : x;
    int off = sel ? WS_XY : WS_XX;
    ws[off + idx]           = p[idx*3+0];
    ws[off +   NROWS + idx] = p[idx*3+1];
    ws[off + 2*NROWS + idx] = p[idx*3+2];
    ws[(sel ? WS_WYA : WS_WXA) + idx] = BLOGF * LOG2E;   // h=0 initial weights
}

// ------------------------------------------------------------- softmin pass
// out[b,i] = -eps*ln2*log2( sum_j 2^{W[j] - ||p_i - q_j||*log2e/eps} )
// dir 0: rows=x, cols=y(SoA)+Wy ; writes fa and folded Wx(nxt)
// dir 1: rows=y, cols=x(SoA)+Wx ; writes ga and folded Wy(nxt)
__global__ __launch_bounds__(256, 4) void softmin_kernel(
    const float* __restrict__ x, const float* __restrict__ y,
    float* __restrict__ ws, int cur,
    float scale_k, float scale_next, int do_avg)
{
    const int dir = blockIdx.z;
    const float* rows = dir ? y : x;

    const float diam      = ws[WS_DIAM];
    const float eps       = fmaxf(diam * scale_k, BLURF);
    const float nie2      = -LOG2E / eps;
    const float eps_next  = fmaxf(diam * scale_next, BLURF);
    const float ien_log2e = LOG2E / eps_next;

    const int tid = threadIdx.x, lane = tid & 63, wid = tid >> 6;
    const int i0  = blockIdx.x * ROWS_PER_BLOCK;
    const int b   = i0 >> 13;
    const int rowbase = i0 + wid * ROWS_PER_WAVE;

    // col SoA base pointers (v2f), per batch b
    const int cbase = dir ? WS_XX : WS_XY;
    const v2f* CX = ((const v2f*)(ws + cbase          )) + b*(NPTS/2);
    const v2f* CY = ((const v2f*)(ws + cbase +   NROWS)) + b*(NPTS/2);
    const v2f* CZ = ((const v2f*)(ws + cbase + 2*NROWS)) + b*(NPTS/2);
    const int wcur_off = dir ? (cur ? WS_WXB : WS_WXA) : (cur ? WS_WYB : WS_WYA);
    const int wnxt_off = dir ? (cur ? WS_WYA : WS_WYB) : (cur ? WS_WXA : WS_WXB);
    const v2f* CW = ((const v2f*)(ws + wcur_off)) + b*(NPTS/2);
    float* Wnxt = ws + wnxt_off;
    float* outf = ws + (dir ? WS_GA : WS_FA);

    float px[ROWS_PER_WAVE], py[ROWS_PER_WAVE], pz[ROWS_PER_WAVE];
    #pragma unroll
    for (int r = 0; r < ROWS_PER_WAVE; ++r) {
        int o = (rowbase + r) * 3;
        px[r] = rows[o]; py[r] = rows[o+1]; pz[r] = rows[o+2];
    }

    v2f m2[ROWS_PER_WAVE], s2[ROWS_PER_WAVE];
    #pragma unroll
    for (int r = 0; r < ROWS_PER_WAVE; ++r) {
        m2[r] = (v2f){-INFINITY,-INFINITY}; s2[r] = (v2f){0.0f,0.0f};
    }

    const v2f nie2v = {nie2, nie2};

    for (int c0 = 0; c0 < NPTS/2; c0 += 256) {     // 512 cols per iter
        v2f Xc[4], Yc[4], Zc[4], Wc[4];
        #pragma unroll
        for (int k = 0; k < 4; ++k) {
            int idx = c0 + k*64 + lane;
            Xc[k] = CX[idx]; Yc[k] = CY[idx]; Zc[k] = CZ[idx]; Wc[k] = CW[idx];
        }
        #pragma unroll
        for (int r = 0; r < ROWS_PER_WAVE; ++r) {
            const v2f prx = {px[r], px[r]}, pry = {py[r], py[r]}, prz = {pz[r], pz[r]};
            v2f w2[4];
            #pragma unroll
            for (int k = 0; k < 4; ++k) {
                v2f dx = Xc[k] - prx, dy = Yc[k] - pry, dz = Zc[k] - prz;
                v2f sq = dx*dx + dy*dy + dz*dz;
                v2f c2; c2.x = FAST_SQRT(sq.x); c2.y = FAST_SQRT(sq.y);
                w2[k] = c2 * nie2v + Wc[k];
            }
            v2f gm = PKMAX(PKMAX(w2[0], w2[1]), PKMAX(w2[2], w2[3]));
            // defer-max (T13): rescale only when the group max beats m by > THR.
            // s-terms stay bounded by 2^THR=256; sum <= 8192*256 fits f32 easily.
            bool need = (gm.x > m2[r].x + DEFER_THR) | (gm.y > m2[r].y + DEFER_THR);
            if (__any(need)) {
                v2f mu = PKMAX(m2[r], gm);
                v2f dm = m2[r] - mu;
                v2f sc; sc.x = RAW_EXP2(dm.x); sc.y = RAW_EXP2(dm.y);  // exp2(-inf)=0 first time
                s2[r] = s2[r] * sc;
                m2[r] = mu;
            }
            v2f e0 = w2[0] - m2[r], e1 = w2[1] - m2[r], e2 = w2[2] - m2[r], e3 = w2[3] - m2[r];
            v2f v0, v1, v2, v3;
            v0.x = RAW_EXP2(e0.x); v0.y = RAW_EXP2(e0.y);
            v1.x = RAW_EXP2(e1.x); v1.y = RAW_EXP2(e1.y);
            v2.x = RAW_EXP2(e2.x); v2.y = RAW_EXP2(e2.y);
            v3.x = RAW_EXP2(e3.x); v3.y = RAW_EXP2(e3.y);
            s2[r] = s2[r] + ((v0 + v1) + (v2 + v3));
        }
    }

    // merge packed halves, then 64-lane butterfly
    #pragma unroll
    for (int r = 0; r < ROWS_PER_WAVE; ++r) {
        float mm = fmaxf(m2[r].x, m2[r].y);
        float ss = s2[r].x * RAW_EXP2(m2[r].x - mm) + s2[r].y * RAW_EXP2(m2[r].y - mm);
        #pragma unroll
        for (int off = 32; off >= 1; off >>= 1) {
            float mo = __shfl_xor(mm, off);
            float so = __shfl_xor(ss, off);
            float mu = fmaxf(mm, mo);
            ss = fmaf(ss, RAW_EXP2(mm-mu), so * RAW_EXP2(mo-mu));
            mm = mu;
        }
        if (lane == 0) {
            float res = -eps * LN2F * (mm + RAW_LOG2(ss));
            int oidx = rowbase + r;
            if (do_avg) res = 0.5f * (outf[oidx] + res);   // in-place: element owned by this thread
            outf[oidx] = res;
            Wnxt[oidx] = fmaf(res, ien_log2e, BLOGF * LOG2E);  // fold for next pass
        }
    }
}

// ----------------------------------------------------------------- reduce
__global__ __launch_bounds__(1024) void reduce_kernel(
    const float* __restrict__ ws, float* __restrict__ out)
{
    const float* f = ws + WS_FA;
    const float* g = ws + WS_GA;
    int tid = threadIdx.x;
    float acc = 0.0f;
    for (int i = tid; i < NROWS; i += 1024) acc += f[i] + g[i];
    #pragma unroll
    for (int off = 32; off >= 1; off >>= 1) acc += __shfl_xor(acc, off);
    __shared__ float sw[16];
    int wid = tid >> 6, lane = tid & 63;
    if (lane == 0) sw[wid] = acc;
    __syncthreads();
    if (tid == 0) {
        float t = 0.0f;
        for (int w = 0; w < 16; ++w) t += sw[w];
        out[0] = t * (1.0f / (float)NROWS);   // mean over B of (sum a*f + sum b*g)
    }
}

// ----------------------------------------------------------------- launch
extern "C" void kernel_launch(void* const* d_in, const int* in_sizes, int n_in,
                              void* d_out, int out_size, void* d_ws, size_t ws_size,
                              hipStream_t stream)
{
    const float* x = (const float*)d_in[0];
    const float* y = (const float*)d_in[1];
    float* out = (float*)d_out;
    float* ws  = (float*)d_ws;

    minmax_kernel<<<1, 1024, 0, stream>>>(x, y, ws + WS_DIAM);
    pack_pts_kernel<<<(NROWS*2)/256, 256, 0, stream>>>(x, y, ws);

    dim3 sgrid(NROWS/ROWS_PER_BLOCK, 1, 2);   // 1024 x 1 x 2 = 2048 blocks
    int cur = 0;

    // init: f0,g0 at eps0; epilogue folds with eps of step 0 (= eps0 again)
    softmin_kernel<<<sgrid, 256, 0, stream>>>(x, y, ws, cur, 1.0f, 1.0f, 0);
    cur ^= 1;

    // 96 Jacobi steps; step k at eps_k = max(diam*0.9^k, blur); fold for k+1
    double sk = 1.0;
    for (int k = 0; k < 96; ++k) {
        float sn = (k < 95) ? (float)(sk * 0.9) : 0.0f;   // last folds at blur
        softmin_kernel<<<sgrid, 256, 0, stream>>>(x, y, ws, cur, (float)sk, sn, 1);
        cur ^= 1;
        sk *= 0.9;
    }

    // final extrapolation at eps = blur (fold output unused)
    softmin_kernel<<<sgrid, 256, 0, stream>>>(x, y, ws, cur, 0.0f, 0.0f, 0);

    reduce_kernel<<<1, 1024, 0, stream>>>(ws, out);
}